// Round 7
// baseline (182.566 us; speedup 1.0000x reference)
//
#include <hip/hip_runtime.h>

typedef unsigned short ushort_t;
typedef __bf16 bf16x8 __attribute__((ext_vector_type(8)));
typedef float f32x4 __attribute__((ext_vector_type(4)));
typedef float f32x2 __attribute__((ext_vector_type(2)));
typedef ushort_t us4 __attribute__((ext_vector_type(4)));

#define T_SOFT 32.0f
#define THRESH 0.76604444311897803f   // cos(40 deg)
#define SW 1048                       // W strip LDS row stride (bf16)
#define SO 648                        // outs strip LDS row stride (bf16)

__device__ __forceinline__ ushort_t f2bf(float f) {
  union { float f; unsigned u; } x; x.f = f;
  unsigned r = (x.u + 0x7fffu + ((x.u >> 16) & 1u)) >> 16;  // RNE
  return (ushort_t)r;
}
__device__ __forceinline__ float bf2f(ushort_t h) {
  union { unsigned u; float f; } x; x.u = ((unsigned)h) << 16; return x.f;
}

// pack 4 fp32 -> 4 bf16 (round-half-up via +0x8000 + byte perm)
__device__ __forceinline__ us4 pack4(float4 x) {
  union { unsigned u[2]; us4 h; } r;
  union { float4 f; unsigned u[4]; } a;
  a.f = x;
  r.u[0] = __builtin_amdgcn_perm(a.u[1] + 0x8000u, a.u[0] + 0x8000u, 0x07060302u);
  r.u[1] = __builtin_amdgcn_perm(a.u[3] + 0x8000u, a.u[2] + 0x8000u, 0x07060302u);
  return r.h;
}
// pack 8 fp32 -> bf16x8
__device__ __forceinline__ bf16x8 pack8(float4 x, float4 y) {
  union { unsigned u[4]; bf16x8 h; } r;
  union { float4 f; unsigned u[4]; } a, b;
  a.f = x; b.f = y;
  r.u[0] = __builtin_amdgcn_perm(a.u[1] + 0x8000u, a.u[0] + 0x8000u, 0x07060302u);
  r.u[1] = __builtin_amdgcn_perm(a.u[3] + 0x8000u, a.u[2] + 0x8000u, 0x07060302u);
  r.u[2] = __builtin_amdgcn_perm(b.u[1] + 0x8000u, b.u[0] + 0x8000u, 0x07060302u);
  r.u[3] = __builtin_amdgcn_perm(b.u[3] + 0x8000u, b.u[2] + 0x8000u, 0x07060302u);
  return r.h;
}

// ---------------- tr3: transposes + attrT + zero-inits ----------------
__global__ __launch_bounds__(256) void tr3_k(const float* __restrict__ s0, ushort_t* __restrict__ d0,
                                             const float* __restrict__ s1, ushort_t* __restrict__ d1,
                                             const float* __restrict__ s2, ushort_t* __restrict__ d2,
                                             const float* __restrict__ s3, ushort_t* __restrict__ d3,
                                             ushort_t* __restrict__ gn_bf,
                                             float* __restrict__ z0, float* __restrict__ z1) {
  int b = blockIdx.x, tid = threadIdx.x;
  if (b >= 1296) {
    if (b == 1296) {          // zero gn_bf rows 1000..1007 (1024 bf16)
      us4 z = {0, 0, 0, 0};
      *reinterpret_cast<us4*>(gn_bf + 1000 * 128 + tid * 4) = z;
    } else if (b < 1361) {    // zero img_h: 65536 float4, 64 blocks
      int local = b - 1297;
      float4 z = make_float4(0.f, 0.f, 0.f, 0.f);
      float4* p = reinterpret_cast<float4*>(z0) + local * 1024 + tid;
      p[0] = z; p[256] = z; p[512] = z; p[768] = z;
    } else {                  // zero proto_redT: 81920 float4, 80 blocks
      int local = b - 1361;
      float4 z = make_float4(0.f, 0.f, 0.f, 0.f);
      float4* p = reinterpret_cast<float4*>(z1) + local * 1024 + tid;
      p[0] = z; p[256] = z; p[512] = z; p[768] = z;
    }
    return;
  }
  __shared__ float tl[32][33];
  const float* src; ushort_t* dst; int R, C, Cw, Rpad, local, ctiles;
  if (b < 640)       { src = s0; dst = d0; R = 2048; C = 312; Cw = 320; Rpad = 2048; local = b;       ctiles = 10; }
  else if (b < 896)  { src = s1; dst = d1; R = 2048; C = 128; Cw = 128; Rpad = 2048; local = b - 640; ctiles = 4;  }
  else if (b < 976)  { src = s2; dst = d2; R = 624;  C = 128; Cw = 128; Rpad = 640;  local = b - 896; ctiles = 4;  }
  else               { src = s3; dst = d3; R = 1000; C = 312; Cw = 312; Rpad = 1024; local = b - 976; ctiles = 10; }
  int rt = local / ctiles, ct = local - rt * ctiles;
  int r0 = rt * 32, c0 = ct * 32;
  #pragma unroll
  for (int p = 0; p < 4; ++p) {
    int idx = p * 256 + tid;
    int rr = idx >> 5, cc = idx & 31;
    float v = 0.f;
    if (r0 + rr < R && c0 + cc < C) v = src[(size_t)(r0 + rr) * C + (c0 + cc)];
    tl[cc][rr] = v;
  }
  __syncthreads();
  int cc = tid >> 3, rq = tid & 7;
  if (c0 + cc < Cw) {   // slim region: cols 312..319 write ZEROS (pad rows of slimT)
    us4 o;
    o[0] = f2bf(tl[cc][rq * 4 + 0]);
    o[1] = f2bf(tl[cc][rq * 4 + 1]);
    o[2] = f2bf(tl[cc][rq * 4 + 2]);
    o[3] = f2bf(tl[cc][rq * 4 + 3]);
    *reinterpret_cast<us4*>(dst + (size_t)(c0 + cc) * Rpad + r0 + rq * 4) = o;
  }
}

// ---------------- split-K GEMM seg: fp32 A (packed in-reg), bf16 BT; atomicAdd fp32 C ----------------
// tile 128 rows x 128 cols, BK=64, nsteps steps
__device__ __forceinline__ void gemm_f32a_seg(
    const float* __restrict__ A, int M, int lda,
    const ushort_t* __restrict__ BT, int ldbt,
    float* __restrict__ C, int ldc,
    int r0, int k0, int nsteps,
    ushort_t* __restrict__ As, ushort_t* __restrict__ Bs, int tid) {
  const int SA = 72;
  int lane = tid & 63, wv = tid >> 6;
  int l15 = lane & 15, quad = lane >> 4;
  int arow = tid >> 4, akq = tid & 15;
  int brow = tid >> 3, bkq = tid & 7;
  const float* agp[8];
  #pragma unroll
  for (int p = 0; p < 8; ++p) {
    int r = r0 + arow + p * 16; if (r >= M) r = M - 1;
    agp[p] = A + (size_t)r * lda + k0 + akq * 4;
  }
  const ushort_t* bgp[4];
  #pragma unroll
  for (int p = 0; p < 4; ++p) bgp[p] = BT + (size_t)(brow + p * 32) * ldbt + k0 + bkq * 8;

  float4 ap[8]; bf16x8 bp[4];
  #pragma unroll
  for (int p = 0; p < 8; ++p) ap[p] = *reinterpret_cast<const float4*>(agp[p]);
  #pragma unroll
  for (int p = 0; p < 4; ++p) bp[p] = *reinterpret_cast<const bf16x8*>(bgp[p]);

  f32x4 acc[2][8];
  #pragma unroll
  for (int i = 0; i < 2; ++i)
    #pragma unroll
    for (int j = 0; j < 8; ++j) acc[i][j] = f32x4{0.f, 0.f, 0.f, 0.f};

  for (int s = 0; s < nsteps; ++s) {
    if (s) __syncthreads();
    #pragma unroll
    for (int p = 0; p < 8; ++p)
      *reinterpret_cast<us4*>(As + (arow + p * 16) * SA + akq * 4) = pack4(ap[p]);
    #pragma unroll
    for (int p = 0; p < 4; ++p)
      *reinterpret_cast<bf16x8*>(Bs + (brow + p * 32) * SA + bkq * 8) = bp[p];
    if (s + 1 < nsteps) {
      #pragma unroll
      for (int p = 0; p < 8; ++p) ap[p] = *reinterpret_cast<const float4*>(agp[p] + 64);
      #pragma unroll
      for (int p = 0; p < 4; ++p) bp[p] = *reinterpret_cast<const bf16x8*>(bgp[p] + 64);
      #pragma unroll
      for (int p = 0; p < 8; ++p) agp[p] += 64;
      #pragma unroll
      for (int p = 0; p < 4; ++p) bgp[p] += 64;
    }
    __syncthreads();
    #pragma unroll
    for (int kh = 0; kh < 2; ++kh) {
      bf16x8 af[2];
      #pragma unroll
      for (int pi = 0; pi < 2; ++pi)
        af[pi] = *reinterpret_cast<bf16x8*>(As + ((wv * 2 + pi) * 16 + l15) * SA + kh * 32 + quad * 8);
      #pragma unroll
      for (int ct = 0; ct < 8; ++ct) {
        bf16x8 bfr = *reinterpret_cast<bf16x8*>(Bs + (ct * 16 + l15) * SA + kh * 32 + quad * 8);
        acc[0][ct] = __builtin_amdgcn_mfma_f32_16x16x32_bf16(af[0], bfr, acc[0][ct], 0, 0, 0);
        acc[1][ct] = __builtin_amdgcn_mfma_f32_16x16x32_bf16(af[1], bfr, acc[1][ct], 0, 0, 0);
      }
    }
  }
  #pragma unroll
  for (int pi = 0; pi < 2; ++pi)
    #pragma unroll
    for (int ct = 0; ct < 8; ++ct) {
      int col = ct * 16 + l15;
      #pragma unroll
      for (int r = 0; r < 4; ++r) {
        int row = r0 + (wv * 2 + pi) * 16 + quad * 4 + r;
        if (row < M) atomicAdd(&C[(size_t)row * ldc + col], acc[pi][ct][r]);
      }
    }
}

// ---------------- split-K GEMM seg: bf16 A, fp32 B (packed in-reg); atomicAdd fp32 out ----------------
// out[m][n] over m in [r0,r0+128), n in [c0,c0+128); out ld = 1024, valid m<320, n<1000
__device__ __forceinline__ void gemm_protoT_seg(
    const ushort_t* __restrict__ A, const float* __restrict__ B,
    float* __restrict__ outp, int r0, int c0, int k0, int nsteps,
    ushort_t* __restrict__ As, ushort_t* __restrict__ Bs, int tid) {
  const int SA = 72;
  int lane = tid & 63, wv = tid >> 6;
  int l15 = lane & 15, quad = lane >> 4;
  int frow = tid >> 4, fkq = tid & 15;   // fp32 staging
  int hrow = tid >> 3, hkq = tid & 7;    // bf16 staging
  const ushort_t* agp[4];
  #pragma unroll
  for (int p = 0; p < 4; ++p) {
    int r = r0 + hrow + p * 32; if (r >= 320) r = 319;
    agp[p] = A + (size_t)r * 2048 + k0 + hkq * 8;
  }
  const float* bgp[8];
  #pragma unroll
  for (int p = 0; p < 8; ++p) {
    int n = c0 + frow + p * 16; if (n >= 1000) n = 999;
    bgp[p] = B + (size_t)n * 2048 + k0 + fkq * 4;
  }
  bf16x8 ar[4]; float4 br[8];
  #pragma unroll
  for (int p = 0; p < 4; ++p) ar[p] = *reinterpret_cast<const bf16x8*>(agp[p]);
  #pragma unroll
  for (int p = 0; p < 8; ++p) br[p] = *reinterpret_cast<const float4*>(bgp[p]);

  f32x4 acc[2][8];
  #pragma unroll
  for (int i = 0; i < 2; ++i)
    #pragma unroll
    for (int j = 0; j < 8; ++j) acc[i][j] = f32x4{0.f, 0.f, 0.f, 0.f};

  for (int s = 0; s < nsteps; ++s) {
    if (s) __syncthreads();
    #pragma unroll
    for (int p = 0; p < 4; ++p)
      *reinterpret_cast<bf16x8*>(As + (hrow + p * 32) * SA + hkq * 8) = ar[p];
    #pragma unroll
    for (int p = 0; p < 8; ++p)
      *reinterpret_cast<us4*>(Bs + (frow + p * 16) * SA + fkq * 4) = pack4(br[p]);
    if (s + 1 < nsteps) {
      #pragma unroll
      for (int p = 0; p < 4; ++p) ar[p] = *reinterpret_cast<const bf16x8*>(agp[p] + 64);
      #pragma unroll
      for (int p = 0; p < 8; ++p) br[p] = *reinterpret_cast<const float4*>(bgp[p] + 64);
      #pragma unroll
      for (int p = 0; p < 4; ++p) agp[p] += 64;
      #pragma unroll
      for (int p = 0; p < 8; ++p) bgp[p] += 64;
    }
    __syncthreads();
    #pragma unroll
    for (int kh = 0; kh < 2; ++kh) {
      bf16x8 af[2];
      #pragma unroll
      for (int pi = 0; pi < 2; ++pi)
        af[pi] = *reinterpret_cast<bf16x8*>(As + ((wv * 2 + pi) * 16 + l15) * SA + kh * 32 + quad * 8);
      #pragma unroll
      for (int ct = 0; ct < 8; ++ct) {
        bf16x8 bfr = *reinterpret_cast<bf16x8*>(Bs + (ct * 16 + l15) * SA + kh * 32 + quad * 8);
        acc[0][ct] = __builtin_amdgcn_mfma_f32_16x16x32_bf16(af[0], bfr, acc[0][ct], 0, 0, 0);
        acc[1][ct] = __builtin_amdgcn_mfma_f32_16x16x32_bf16(af[1], bfr, acc[1][ct], 0, 0, 0);
      }
    }
  }
  #pragma unroll
  for (int pi = 0; pi < 2; ++pi)
    #pragma unroll
    for (int ct = 0; ct < 8; ++ct) {
      int n = c0 + ct * 16 + l15;
      if (n < 1000) {
        #pragma unroll
        for (int r = 0; r < 4; ++r) {
          int m = r0 + (wv * 2 + pi) * 16 + quad * 4 + r;
          if (m < 320) atomicAdd(&outp[(size_t)m * 1024 + n], acc[pi][ct][r]);
        }
      }
    }
}

// ---------------- mega: img_h split-K (128) + proto_redT split-K (192) + gn (125) ----------------
__global__ __launch_bounds__(256, 4) void mega_k(
    const float* __restrict__ attributes, const float* __restrict__ att_g,
    ushort_t* __restrict__ gn_bf,
    const float* __restrict__ img_proto, const ushort_t* __restrict__ slimT,
    const float* __restrict__ image_feats, const ushort_t* __restrict__ imgwT,
    float* __restrict__ img_h, float* __restrict__ proto_redT) {
  __shared__ ushort_t As[128 * 72];
  __shared__ ushort_t Bs[128 * 72];
  int b = blockIdx.x, tid = threadIdx.x;
  if (b < 128) {               // img_h: 16 row-tiles x 8 K-chunks (K=256, 4 steps)
    int tile = b >> 3, kc = b & 7;
    gemm_f32a_seg(image_feats, 2048, 2048, imgwT, 2048, img_h, 128,
                  tile * 128, kc * 256, 4, As, Bs, tid);
    return;
  }
  if (b < 320) {               // proto_redT: 24 tiles (3 rb x 8 cb) x 8 K-chunks
    int idx = b - 128;
    int tile = idx >> 3, kc = idx & 7;
    int rb = tile / 8, cb = tile - rb * 8;
    gemm_protoT_seg(slimT, img_proto, proto_redT, rb * 128, cb * 128, kc * 256, 4, As, Bs, tid);
    return;
  }
  // gn: 125 blocks; reuse As/Bs LDS
  b -= 320;
  float* a_lds = reinterpret_cast<float*>(As);   // [8][316] = 10112 B <= 18432
  float* red2 = reinterpret_cast<float*>(Bs);    // [8][2]
  int h = tid & 127;
  int c0 = b * 8;
  for (int idx = tid; idx < 8 * 312; idx += 256) {
    int r = idx / 312;
    int k = idx - r * 312;
    a_lds[r * 316 + k] = attributes[(c0 + r) * 312 + k];
  }
  __syncthreads();
  float acc[8] = {0.f,0.f,0.f,0.f,0.f,0.f,0.f,0.f};
  for (int k = 0; k < 312; k += 4) {
    float w0 = att_g[(k + 0) * 128 + h];
    float w1 = att_g[(k + 1) * 128 + h];
    float w2 = att_g[(k + 2) * 128 + h];
    float w3 = att_g[(k + 3) * 128 + h];
    #pragma unroll
    for (int r = 0; r < 8; ++r) {
      float4 a4 = *reinterpret_cast<const float4*>(&a_lds[r * 316 + k]);
      acc[r] += a4.x * w0 + a4.y * w1 + a4.z * w2 + a4.w * w3;
    }
  }
  int lane = tid & 63, wvid = (tid >> 6) & 1;
  #pragma unroll
  for (int r = 0; r < 8; ++r) {
    float v = acc[r] * acc[r];
    #pragma unroll
    for (int off = 32; off > 0; off >>= 1) v += __shfl_xor(v, off, 64);
    if (lane == 0) red2[r * 2 + wvid] = v;   // duplicate waves write identical values
  }
  __syncthreads();
  #pragma unroll
  for (int r = 0; r < 8; ++r) {
    float nrm = fmaxf(sqrtf(red2[r * 2 + 0] + red2[r * 2 + 1]), 1e-12f);
    gn_bf[(c0 + r) * 128 + h] = f2bf(acc[r] / nrm);
  }
}

// ---------------- attn4: sim -> masked softmax -> propagate -> ph, all fused ----------------
__global__ __launch_bounds__(256) void attn4_k(
    const ushort_t* __restrict__ gn_bf, const ushort_t* __restrict__ attrT,
    const float* __restrict__ proto_redT,
    const float* __restrict__ slim_b, const ushort_t* __restrict__ protowT,
    const float* __restrict__ proto_b, float* __restrict__ ph) {
  __shared__ ushort_t W[16 * SW];
  __shared__ ushort_t OS[16 * SO];
  __shared__ float rsum[16];
  __shared__ int flags[63];
  int tid = threadIdx.x;
  int i0 = blockIdx.x * 16;
  int lane = tid & 63, wv = tid >> 6;
  int l15 = lane & 15, quad = lane >> 4;
  if (tid < 63) flags[tid] = 0;
  if (tid >= 64 && tid < 80) rsum[tid - 64] = 0.f;
  W[(tid >> 4) * SW + 1008 + (tid & 15)] = 0;   // zero k-pad cols 1008..1023
  __syncthreads();

  // phase 1: sim rows i0..i0+15 vs all j; exp; W strip -> LDS; rowsums; hot flags
  const ushort_t* abase = gn_bf + (size_t)(i0 + l15) * 128 + quad * 8;
  bf16x8 af0 = *reinterpret_cast<const bf16x8*>(abase);
  bf16x8 af1 = *reinterpret_cast<const bf16x8*>(abase + 32);
  bf16x8 af2 = *reinterpret_cast<const bf16x8*>(abase + 64);
  bf16x8 af3 = *reinterpret_cast<const bf16x8*>(abase + 96);
  float rs[4] = {0.f, 0.f, 0.f, 0.f};
  for (int jt = wv; jt < 63; jt += 4) {
    const ushort_t* bbase = gn_bf + (size_t)(jt * 16 + l15) * 128 + quad * 8;
    f32x4 d = {0.f, 0.f, 0.f, 0.f};
    d = __builtin_amdgcn_mfma_f32_16x16x32_bf16(af0, *reinterpret_cast<const bf16x8*>(bbase),      d, 0, 0, 0);
    d = __builtin_amdgcn_mfma_f32_16x16x32_bf16(af1, *reinterpret_cast<const bf16x8*>(bbase + 32), d, 0, 0, 0);
    d = __builtin_amdgcn_mfma_f32_16x16x32_bf16(af2, *reinterpret_cast<const bf16x8*>(bbase + 64), d, 0, 0, 0);
    d = __builtin_amdgcn_mfma_f32_16x16x32_bf16(af3, *reinterpret_cast<const bf16x8*>(bbase + 96), d, 0, 0, 0);
    int hot = 0;
    #pragma unroll
    for (int r = 0; r < 4; ++r) {
      float w = 0.f;
      if (d[r] > THRESH) { w = __expf(T_SOFT * (d[r] - 1.0f)); hot = 1; }  // shift cancels in normalize
      ushort_t wb = f2bf(w);
      W[(quad * 4 + r) * SW + jt * 16 + l15] = wb;
      rs[r] += bf2f(wb);    // rowsum of ROUNDED weights
    }
    if (hot) flags[jt] = 1;
  }
  #pragma unroll
  for (int r = 0; r < 4; ++r) {
    float v = rs[r];
    v += __shfl_xor(v, 1, 64); v += __shfl_xor(v, 2, 64);
    v += __shfl_xor(v, 4, 64); v += __shfl_xor(v, 8, 64);
    if (l15 == 0) atomicAdd(&rsum[quad * 4 + r], v);
  }
  __syncthreads();

  // phase 2: outs_strip = W @ [attrT; proto_redT; 0]^T (skip cold k-tiles)
  f32x4 acc[10];
  #pragma unroll
  for (int t = 0; t < 10; ++t) acc[t] = f32x4{0.f, 0.f, 0.f, 0.f};
  for (int s = 0; s < 32; ++s) {
    int f = flags[2 * s] | ((2 * s + 1 < 63) ? flags[2 * s + 1] : 0);
    if (!f) continue;
    bf16x8 a = *reinterpret_cast<bf16x8*>(W + l15 * SW + s * 32 + quad * 8);
    #pragma unroll
    for (int t = 0; t < 10; ++t) {
      int nrow = (wv * 10 + t) * 16 + l15;
      bf16x8 bfr;
      if (nrow < 312) {
        bfr = *reinterpret_cast<const bf16x8*>(attrT + (size_t)nrow * 1024 + s * 32 + quad * 8);
      } else if (nrow < 632) {
        const float* pp = proto_redT + (size_t)(nrow - 312) * 1024 + s * 32 + quad * 8;
        bfr = pack8(*reinterpret_cast<const float4*>(pp), *reinterpret_cast<const float4*>(pp + 4));
      } else {
        union { unsigned u[4]; bf16x8 h; } z = {{0u, 0u, 0u, 0u}};
        bfr = z.h;
      }
      acc[t] = __builtin_amdgcn_mfma_f32_16x16x32_bf16(a, bfr, acc[t], 0, 0, 0);
    }
  }
  // normalize + bias -> OS (A-layout for phase 3)
  #pragma unroll
  for (int t = 0; t < 10; ++t) {
    int col = (wv * 10 + t) * 16 + l15;   // 0..639
    float bias = (col >= 312 && col < 624) ? slim_b[col - 312] : 0.f;
    #pragma unroll
    for (int r = 0; r < 4; ++r) {
      int row = quad * 4 + r;
      float inv = 1.f / fmaxf(rsum[row], 1e-30f);
      OS[row * SO + col] = f2bf(acc[t][r] * inv + bias);
    }
  }
  __syncthreads();

  // phase 3: ph_strip = OS(16x640) @ protowT(128x640)^T + proto_b
  f32x4 acc2[2];
  acc2[0] = f32x4{0.f, 0.f, 0.f, 0.f};
  acc2[1] = f32x4{0.f, 0.f, 0.f, 0.f};
  for (int s = 0; s < 20; ++s) {
    bf16x8 a = *reinterpret_cast<bf16x8*>(OS + l15 * SO + s * 32 + quad * 8);
    #pragma unroll
    for (int t = 0; t < 2; ++t) {
      int n = (wv * 2 + t) * 16 + l15;
      bf16x8 bfr = *reinterpret_cast<const bf16x8*>(protowT + (size_t)n * 640 + s * 32 + quad * 8);
      acc2[t] = __builtin_amdgcn_mfma_f32_16x16x32_bf16(a, bfr, acc2[t], 0, 0, 0);
    }
  }
  #pragma unroll
  for (int t = 0; t < 2; ++t) {
    int h = (wv * 2 + t) * 16 + l15;
    float pb = proto_b[h];
    #pragma unroll
    for (int r = 0; r < 4; ++r) {
      int gi = i0 + quad * 4 + r;
      if (gi < 1000) ph[(size_t)gi * 128 + h] = acc2[t][r] + pb;
    }
  }
}

// ---------------- final: out[b,c] = fc_b + sum_h relu(img_h[b,h]+ph[c,h]) * fc_w[h] ----------------
__global__ __launch_bounds__(256) void final_k(
    const float* __restrict__ img_h, const float* __restrict__ ph,
    const float* __restrict__ fc_w, const float* __restrict__ fc_b,
    float* __restrict__ out) {
  __shared__ float ih[128][132];
  __shared__ float ps[64][132];
  __shared__ float ws_[128];
  int tid = threadIdx.x;
  int b0 = blockIdx.x * 128;
  int c0 = blockIdx.y * 64;
  for (int idx = tid; idx < 4096; idx += 256) {
    int row = idx >> 5, c4 = (idx & 31) * 4;
    float4 v = *reinterpret_cast<const float4*>(img_h + (size_t)(b0 + row) * 128 + c4);
    *reinterpret_cast<float4*>(&ih[row][c4]) = v;
  }
  for (int idx = tid; idx < 2048; idx += 256) {
    int row = idx >> 5, c4 = (idx & 31) * 4;
    int c = c0 + row;
    float4 v = make_float4(0.f, 0.f, 0.f, 0.f);
    if (c < 1000) v = *reinterpret_cast<const float4*>(ph + (size_t)c * 128 + c4);
    *reinterpret_cast<float4*>(&ps[row][c4]) = v;
  }
  if (tid < 128) ws_[tid] = fc_w[tid];
  __syncthreads();
  int tx = tid & 15, ty = tid >> 4;
  f32x2 acc[8][4] = {};
  const f32x2 zero2 = {0.f, 0.f};
  for (int h = 0; h < 128; h += 4) {
    float4 w4 = *reinterpret_cast<float4*>(&ws_[h]);
    f32x2 wlo = {w4.x, w4.y}, whi = {w4.z, w4.w};
    float4 a4[8], p4[4];
    #pragma unroll
    for (int i = 0; i < 8; ++i) a4[i] = *reinterpret_cast<float4*>(&ih[ty * 8 + i][h]);
    #pragma unroll
    for (int j = 0; j < 4; ++j) p4[j] = *reinterpret_cast<float4*>(&ps[tx * 4 + j][h]);
    #pragma unroll
    for (int i = 0; i < 8; ++i) {
      f32x2 alo = {a4[i].x, a4[i].y}, ahi = {a4[i].z, a4[i].w};
      #pragma unroll
      for (int j = 0; j < 4; ++j) {
        f32x2 plo = {p4[j].x, p4[j].y}, phi = {p4[j].z, p4[j].w};
        f32x2 t0 = __builtin_elementwise_max(alo + plo, zero2);
        f32x2 t1 = __builtin_elementwise_max(ahi + phi, zero2);
        acc[i][j] = acc[i][j] + t0 * wlo;
        acc[i][j] = acc[i][j] + t1 * whi;
      }
    }
  }
  float fb = fc_b[0];
  #pragma unroll
  for (int i = 0; i < 8; ++i) {
    int b = b0 + ty * 8 + i;
    int c = c0 + tx * 4;
    if (c < 1000) {
      float4 v = make_float4(acc[i][0].x + acc[i][0].y + fb, acc[i][1].x + acc[i][1].y + fb,
                             acc[i][2].x + acc[i][2].y + fb, acc[i][3].x + acc[i][3].y + fb);
      *reinterpret_cast<float4*>(out + (size_t)b * 1000 + c) = v;
    }
  }
}

extern "C" void kernel_launch(void* const* d_in, const int* in_sizes, int n_in,
                              void* d_out, int out_size, void* d_ws, size_t ws_size,
                              hipStream_t stream) {
  const float* image_feats = (const float*)d_in[0];   // [2048,2048]
  const float* img_proto   = (const float*)d_in[1];   // [1000,2048]
  const float* attributes  = (const float*)d_in[2];   // [1000,312]
  const float* att_g   = (const float*)d_in[4];       // [312,128]
  const float* slim_w  = (const float*)d_in[5];       // [2048,312]
  const float* slim_b  = (const float*)d_in[6];       // [312]
  const float* img_w   = (const float*)d_in[7];       // [2048,128]
  const float* proto_w = (const float*)d_in[8];       // [624,128]
  const float* proto_b = (const float*)d_in[9];       // [1,128]
  const float* fc_w    = (const float*)d_in[10];      // [128,1]
  const float* fc_b    = (const float*)d_in[11];      // [1]
  float* out = (float*)d_out;                         // [2048,1000]

  char* ws = (char*)d_ws;
  size_t o = 0;
  auto alloc = [&](size_t bytes) { size_t r = o; o += (bytes + 255) & ~(size_t)255; return r; };
  ushort_t* imgwT   = (ushort_t*)(ws + alloc(128ull * 2048 * 2));   // img_w^T bf16
  ushort_t* slimT   = (ushort_t*)(ws + alloc(320ull * 2048 * 2));   // slim_w^T bf16, rows 312..319 ZERO
  ushort_t* protowT = (ushort_t*)(ws + alloc(128ull * 640 * 2));    // proto_w^T bf16, K-pad zeros
  ushort_t* gn_bf   = (ushort_t*)(ws + alloc(1008ull * 128 * 2));   // normalized g bf16, tail zero
  ushort_t* attrT   = (ushort_t*)(ws + alloc(312ull * 1024 * 2));   // attributes^T bf16
  float* proto_redT = (float*)(ws + alloc(320ull * 1024 * 4));      // proto_red^T fp32 (split-K atomics)
  float* img_h     = (float*)(ws + alloc(2048ull * 128 * 4));       // split-K atomics
  float* ph        = (float*)(ws + alloc(1000ull * 128 * 4));

  // transposes (976) + attrT (320) + gn tail (1) + zero img_h (64) + zero proto_redT (80)
  tr3_k<<<1441, 256, 0, stream>>>(slim_w, slimT, img_w, imgwT, proto_w, protowT,
                                  attributes, attrT, gn_bf, img_h, proto_redT);

  // img_h split-K (128) + proto_redT split-K (192) + gn (125)
  mega_k<<<445, 256, 0, stream>>>(attributes, att_g, gn_bf,
                                  img_proto, slimT,
                                  image_feats, imgwT, img_h, proto_redT);

  // sim -> softmax -> propagate -> ph (fused)
  attn4_k<<<63, 256, 0, stream>>>(gn_bf, attrT, proto_redT, slim_b, protowT, proto_b, ph);

  final_k<<<dim3(16, 16), 256, 0, stream>>>(img_h, ph, fc_w, fc_b, out);
}

// Round 8
// 176.362 us; speedup vs baseline: 1.0352x; 1.0352x over previous
//
#include <hip/hip_runtime.h>

typedef unsigned short ushort_t;
typedef __bf16 bf16x8 __attribute__((ext_vector_type(8)));
typedef float f32x4 __attribute__((ext_vector_type(4)));
typedef float f32x2 __attribute__((ext_vector_type(2)));
typedef ushort_t us4 __attribute__((ext_vector_type(4)));

#define T_SOFT 32.0f
#define THRESH 0.76604444311897803f   // cos(40 deg)
#define SW 1048                       // W strip LDS row stride (bf16)
#define SO 648                        // outs strip LDS row stride (bf16)
#define PIH (2048 * 128)              // img_h partial stride (floats)
#define PPR (320 * 1024)              // proto_redT partial stride (floats)

__device__ __forceinline__ ushort_t f2bf(float f) {
  union { float f; unsigned u; } x; x.f = f;
  unsigned r = (x.u + 0x7fffu + ((x.u >> 16) & 1u)) >> 16;  // RNE
  return (ushort_t)r;
}
__device__ __forceinline__ float bf2f(ushort_t h) {
  union { unsigned u; float f; } x; x.u = ((unsigned)h) << 16; return x.f;
}

// pack 4 fp32 -> 4 bf16 (round-half-up via +0x8000 + byte perm)
__device__ __forceinline__ us4 pack4(float4 x) {
  union { unsigned u[2]; us4 h; } r;
  union { float4 f; unsigned u[4]; } a;
  a.f = x;
  r.u[0] = __builtin_amdgcn_perm(a.u[1] + 0x8000u, a.u[0] + 0x8000u, 0x07060302u);
  r.u[1] = __builtin_amdgcn_perm(a.u[3] + 0x8000u, a.u[2] + 0x8000u, 0x07060302u);
  return r.h;
}
// pack 8 fp32 -> bf16x8
__device__ __forceinline__ bf16x8 pack8(f32x4 x, f32x4 y) {
  union { unsigned u[4]; bf16x8 h; } r;
  union { f32x4 f; unsigned u[4]; } a, b;
  a.f = x; b.f = y;
  r.u[0] = __builtin_amdgcn_perm(a.u[1] + 0x8000u, a.u[0] + 0x8000u, 0x07060302u);
  r.u[1] = __builtin_amdgcn_perm(a.u[3] + 0x8000u, a.u[2] + 0x8000u, 0x07060302u);
  r.u[2] = __builtin_amdgcn_perm(b.u[1] + 0x8000u, b.u[0] + 0x8000u, 0x07060302u);
  r.u[3] = __builtin_amdgcn_perm(b.u[3] + 0x8000u, b.u[2] + 0x8000u, 0x07060302u);
  return r.h;
}

// ---------------- tr3: transposes + attrT + gn tail zero ----------------
__global__ __launch_bounds__(256) void tr3_k(const float* __restrict__ s0, ushort_t* __restrict__ d0,
                                             const float* __restrict__ s1, ushort_t* __restrict__ d1,
                                             const float* __restrict__ s2, ushort_t* __restrict__ d2,
                                             const float* __restrict__ s3, ushort_t* __restrict__ d3,
                                             ushort_t* __restrict__ gn_bf) {
  int b = blockIdx.x, tid = threadIdx.x;
  if (b >= 1296) {              // zero gn_bf rows 1000..1007 (1024 bf16)
    us4 z = {0, 0, 0, 0};
    *reinterpret_cast<us4*>(gn_bf + 1000 * 128 + tid * 4) = z;
    return;
  }
  __shared__ float tl[32][33];
  const float* src; ushort_t* dst; int R, C, Cw, Rpad, local, ctiles;
  if (b < 640)       { src = s0; dst = d0; R = 2048; C = 312; Cw = 320; Rpad = 2048; local = b;       ctiles = 10; }
  else if (b < 896)  { src = s1; dst = d1; R = 2048; C = 128; Cw = 128; Rpad = 2048; local = b - 640; ctiles = 4;  }
  else if (b < 976)  { src = s2; dst = d2; R = 624;  C = 128; Cw = 128; Rpad = 640;  local = b - 896; ctiles = 4;  }
  else               { src = s3; dst = d3; R = 1000; C = 312; Cw = 312; Rpad = 1024; local = b - 976; ctiles = 10; }
  int rt = local / ctiles, ct = local - rt * ctiles;
  int r0 = rt * 32, c0 = ct * 32;
  #pragma unroll
  for (int p = 0; p < 4; ++p) {
    int idx = p * 256 + tid;
    int rr = idx >> 5, cc = idx & 31;
    float v = 0.f;
    if (r0 + rr < R && c0 + cc < C) v = src[(size_t)(r0 + rr) * C + (c0 + cc)];
    tl[cc][rr] = v;
  }
  __syncthreads();
  int cc = tid >> 3, rq = tid & 7;
  if (c0 + cc < Cw) {   // slim region: cols 312..319 write ZEROS (pad rows of slimT)
    us4 o;
    o[0] = f2bf(tl[cc][rq * 4 + 0]);
    o[1] = f2bf(tl[cc][rq * 4 + 1]);
    o[2] = f2bf(tl[cc][rq * 4 + 2]);
    o[3] = f2bf(tl[cc][rq * 4 + 3]);
    *reinterpret_cast<us4*>(dst + (size_t)(c0 + cc) * Rpad + r0 + rq * 4) = o;
  }
}

// ---------------- split-K GEMM seg: fp32 A (packed in-reg), bf16 BT; DIRECT store to partial ----------------
// tile 128 rows x 128 cols, BK=64
__device__ __forceinline__ void gemm_f32a_seg(
    const float* __restrict__ A, int lda,
    const ushort_t* __restrict__ BT, int ldbt,
    float* __restrict__ Cpart, int ldc,
    int r0, int k0, int nsteps,
    ushort_t* __restrict__ As, ushort_t* __restrict__ Bs, int tid) {
  const int SA = 72;
  int lane = tid & 63, wv = tid >> 6;
  int l15 = lane & 15, quad = lane >> 4;
  int arow = tid >> 4, akq = tid & 15;
  int brow = tid >> 3, bkq = tid & 7;
  const float* agp[8];
  #pragma unroll
  for (int p = 0; p < 8; ++p) agp[p] = A + (size_t)(r0 + arow + p * 16) * lda + k0 + akq * 4;
  const ushort_t* bgp[4];
  #pragma unroll
  for (int p = 0; p < 4; ++p) bgp[p] = BT + (size_t)(brow + p * 32) * ldbt + k0 + bkq * 8;

  float4 ap[8]; bf16x8 bp[4];
  #pragma unroll
  for (int p = 0; p < 8; ++p) ap[p] = *reinterpret_cast<const float4*>(agp[p]);
  #pragma unroll
  for (int p = 0; p < 4; ++p) bp[p] = *reinterpret_cast<const bf16x8*>(bgp[p]);

  f32x4 acc[2][8];
  #pragma unroll
  for (int i = 0; i < 2; ++i)
    #pragma unroll
    for (int j = 0; j < 8; ++j) acc[i][j] = f32x4{0.f, 0.f, 0.f, 0.f};

  for (int s = 0; s < nsteps; ++s) {
    if (s) __syncthreads();
    #pragma unroll
    for (int p = 0; p < 8; ++p)
      *reinterpret_cast<us4*>(As + (arow + p * 16) * SA + akq * 4) = pack4(ap[p]);
    #pragma unroll
    for (int p = 0; p < 4; ++p)
      *reinterpret_cast<bf16x8*>(Bs + (brow + p * 32) * SA + bkq * 8) = bp[p];
    if (s + 1 < nsteps) {
      #pragma unroll
      for (int p = 0; p < 8; ++p) ap[p] = *reinterpret_cast<const float4*>(agp[p] + 64);
      #pragma unroll
      for (int p = 0; p < 4; ++p) bp[p] = *reinterpret_cast<const bf16x8*>(bgp[p] + 64);
      #pragma unroll
      for (int p = 0; p < 8; ++p) agp[p] += 64;
      #pragma unroll
      for (int p = 0; p < 4; ++p) bgp[p] += 64;
    }
    __syncthreads();
    #pragma unroll
    for (int kh = 0; kh < 2; ++kh) {
      bf16x8 af[2];
      #pragma unroll
      for (int pi = 0; pi < 2; ++pi)
        af[pi] = *reinterpret_cast<bf16x8*>(As + ((wv * 2 + pi) * 16 + l15) * SA + kh * 32 + quad * 8);
      #pragma unroll
      for (int ct = 0; ct < 8; ++ct) {
        bf16x8 bfr = *reinterpret_cast<bf16x8*>(Bs + (ct * 16 + l15) * SA + kh * 32 + quad * 8);
        acc[0][ct] = __builtin_amdgcn_mfma_f32_16x16x32_bf16(af[0], bfr, acc[0][ct], 0, 0, 0);
        acc[1][ct] = __builtin_amdgcn_mfma_f32_16x16x32_bf16(af[1], bfr, acc[1][ct], 0, 0, 0);
      }
    }
  }
  #pragma unroll
  for (int pi = 0; pi < 2; ++pi)
    #pragma unroll
    for (int ct = 0; ct < 8; ++ct) {
      int col = ct * 16 + l15;
      #pragma unroll
      for (int r = 0; r < 4; ++r) {
        int row = r0 + (wv * 2 + pi) * 16 + quad * 4 + r;
        Cpart[(size_t)row * ldc + col] = acc[pi][ct][r];
      }
    }
}

// ---------------- split-K GEMM seg: bf16 A, fp32 B (packed in-reg); DIRECT store to partial ----------------
// out rows m in [r0,r0+128) (valid m<320), cols n in [c0,c0+128) (n>=1000 stores clamped-row garbage,
// masked later by W=0); ld 1024
__device__ __forceinline__ void gemm_protoT_seg(
    const ushort_t* __restrict__ A, const float* __restrict__ B,
    float* __restrict__ outp, int r0, int c0, int k0, int nsteps,
    ushort_t* __restrict__ As, ushort_t* __restrict__ Bs, int tid) {
  const int SA = 72;
  int lane = tid & 63, wv = tid >> 6;
  int l15 = lane & 15, quad = lane >> 4;
  int frow = tid >> 4, fkq = tid & 15;
  int hrow = tid >> 3, hkq = tid & 7;
  const ushort_t* agp[4];
  #pragma unroll
  for (int p = 0; p < 4; ++p) {
    int r = r0 + hrow + p * 32; if (r >= 320) r = 319;
    agp[p] = A + (size_t)r * 2048 + k0 + hkq * 8;
  }
  const float* bgp[8];
  #pragma unroll
  for (int p = 0; p < 8; ++p) {
    int n = c0 + frow + p * 16; if (n >= 1000) n = 999;
    bgp[p] = B + (size_t)n * 2048 + k0 + fkq * 4;
  }
  bf16x8 ar[4]; float4 br[8];
  #pragma unroll
  for (int p = 0; p < 4; ++p) ar[p] = *reinterpret_cast<const bf16x8*>(agp[p]);
  #pragma unroll
  for (int p = 0; p < 8; ++p) br[p] = *reinterpret_cast<const float4*>(bgp[p]);

  f32x4 acc[2][8];
  #pragma unroll
  for (int i = 0; i < 2; ++i)
    #pragma unroll
    for (int j = 0; j < 8; ++j) acc[i][j] = f32x4{0.f, 0.f, 0.f, 0.f};

  for (int s = 0; s < nsteps; ++s) {
    if (s) __syncthreads();
    #pragma unroll
    for (int p = 0; p < 4; ++p)
      *reinterpret_cast<bf16x8*>(As + (hrow + p * 32) * SA + hkq * 8) = ar[p];
    #pragma unroll
    for (int p = 0; p < 8; ++p)
      *reinterpret_cast<us4*>(Bs + (frow + p * 16) * SA + fkq * 4) = pack4(br[p]);
    if (s + 1 < nsteps) {
      #pragma unroll
      for (int p = 0; p < 4; ++p) ar[p] = *reinterpret_cast<const bf16x8*>(agp[p] + 64);
      #pragma unroll
      for (int p = 0; p < 8; ++p) br[p] = *reinterpret_cast<const float4*>(bgp[p] + 64);
      #pragma unroll
      for (int p = 0; p < 4; ++p) agp[p] += 64;
      #pragma unroll
      for (int p = 0; p < 8; ++p) bgp[p] += 64;
    }
    __syncthreads();
    #pragma unroll
    for (int kh = 0; kh < 2; ++kh) {
      bf16x8 af[2];
      #pragma unroll
      for (int pi = 0; pi < 2; ++pi)
        af[pi] = *reinterpret_cast<bf16x8*>(As + ((wv * 2 + pi) * 16 + l15) * SA + kh * 32 + quad * 8);
      #pragma unroll
      for (int ct = 0; ct < 8; ++ct) {
        bf16x8 bfr = *reinterpret_cast<bf16x8*>(Bs + (ct * 16 + l15) * SA + kh * 32 + quad * 8);
        acc[0][ct] = __builtin_amdgcn_mfma_f32_16x16x32_bf16(af[0], bfr, acc[0][ct], 0, 0, 0);
        acc[1][ct] = __builtin_amdgcn_mfma_f32_16x16x32_bf16(af[1], bfr, acc[1][ct], 0, 0, 0);
      }
    }
  }
  #pragma unroll
  for (int pi = 0; pi < 2; ++pi)
    #pragma unroll
    for (int ct = 0; ct < 8; ++ct) {
      int n = c0 + ct * 16 + l15;
      #pragma unroll
      for (int r = 0; r < 4; ++r) {
        int m = r0 + (wv * 2 + pi) * 16 + quad * 4 + r;
        if (m < 320) outp[(size_t)m * 1024 + n] = acc[pi][ct][r];
      }
    }
}

// ---------------- mega: img_h splitK x4 (64) + proto_redT splitK x4 (96) + gn (125) ----------------
__global__ __launch_bounds__(256) void mega_k(
    const float* __restrict__ attributes, const float* __restrict__ att_g,
    ushort_t* __restrict__ gn_bf,
    const float* __restrict__ img_proto, const ushort_t* __restrict__ slimT,
    const float* __restrict__ image_feats, const ushort_t* __restrict__ imgwT,
    float* __restrict__ img_hP, float* __restrict__ proto_redP) {
  __shared__ ushort_t As[128 * 72];
  __shared__ ushort_t Bs[128 * 72];
  int b = blockIdx.x, tid = threadIdx.x;
  if (b < 64) {                // img_h: 16 row-tiles x 4 K-chunks (K=512, 8 steps)
    int tile = b >> 2, kc = b & 3;
    gemm_f32a_seg(image_feats, 2048, imgwT, 2048, img_hP + (size_t)kc * PIH, 128,
                  tile * 128, kc * 512, 8, As, Bs, tid);
    return;
  }
  if (b < 160) {               // proto_redT: 24 tiles (3 rb x 8 cb) x 4 K-chunks
    int idx = b - 64;
    int tile = idx >> 2, kc = idx & 3;
    int rb = tile >> 3, cb = tile & 7;
    gemm_protoT_seg(slimT, img_proto, proto_redP + (size_t)kc * PPR,
                    rb * 128, cb * 128, kc * 512, 8, As, Bs, tid);
    return;
  }
  // gn: 125 blocks; reuse As/Bs LDS
  b -= 160;
  float* a_lds = reinterpret_cast<float*>(As);   // [8][316] = 10112 B <= 18432
  float* red2 = reinterpret_cast<float*>(Bs);    // [8][2]
  int h = tid & 127;
  int c0 = b * 8;
  for (int idx = tid; idx < 8 * 312; idx += 256) {
    int r = idx / 312;
    int k = idx - r * 312;
    a_lds[r * 316 + k] = attributes[(c0 + r) * 312 + k];
  }
  __syncthreads();
  float acc[8] = {0.f,0.f,0.f,0.f,0.f,0.f,0.f,0.f};
  for (int k = 0; k < 312; k += 4) {
    float w0 = att_g[(k + 0) * 128 + h];
    float w1 = att_g[(k + 1) * 128 + h];
    float w2 = att_g[(k + 2) * 128 + h];
    float w3 = att_g[(k + 3) * 128 + h];
    #pragma unroll
    for (int r = 0; r < 8; ++r) {
      float4 a4 = *reinterpret_cast<const float4*>(&a_lds[r * 316 + k]);
      acc[r] += a4.x * w0 + a4.y * w1 + a4.z * w2 + a4.w * w3;
    }
  }
  int lane = tid & 63, wvid = (tid >> 6) & 1;
  #pragma unroll
  for (int r = 0; r < 8; ++r) {
    float v = acc[r] * acc[r];
    #pragma unroll
    for (int off = 32; off > 0; off >>= 1) v += __shfl_xor(v, off, 64);
    if (lane == 0) red2[r * 2 + wvid] = v;   // duplicate waves write identical values
  }
  __syncthreads();
  #pragma unroll
  for (int r = 0; r < 8; ++r) {
    float nrm = fmaxf(sqrtf(red2[r * 2 + 0] + red2[r * 2 + 1]), 1e-12f);
    gn_bf[(c0 + r) * 128 + h] = f2bf(acc[r] / nrm);
  }
}

// ---------------- attn4: sim -> masked softmax -> propagate -> ph, all fused ----------------
__global__ __launch_bounds__(256) void attn4_k(
    const ushort_t* __restrict__ gn_bf, const ushort_t* __restrict__ attrT,
    const float* __restrict__ proto_redP,
    const float* __restrict__ slim_b, const ushort_t* __restrict__ protowT,
    const float* __restrict__ proto_b, float* __restrict__ ph) {
  __shared__ ushort_t W[16 * SW];
  __shared__ ushort_t OS[16 * SO];
  __shared__ float rsum[16];
  __shared__ int flags[63];
  int tid = threadIdx.x;
  int i0 = blockIdx.x * 16;
  int lane = tid & 63, wv = tid >> 6;
  int l15 = lane & 15, quad = lane >> 4;
  if (tid < 63) flags[tid] = 0;
  if (tid >= 64 && tid < 80) rsum[tid - 64] = 0.f;
  W[(tid >> 4) * SW + 1008 + (tid & 15)] = 0;   // zero k-pad cols 1008..1023
  __syncthreads();

  // phase 1: sim rows i0..i0+15 vs all j; exp; W strip -> LDS; rowsums; hot flags
  const ushort_t* abase = gn_bf + (size_t)(i0 + l15) * 128 + quad * 8;
  bf16x8 af0 = *reinterpret_cast<const bf16x8*>(abase);
  bf16x8 af1 = *reinterpret_cast<const bf16x8*>(abase + 32);
  bf16x8 af2 = *reinterpret_cast<const bf16x8*>(abase + 64);
  bf16x8 af3 = *reinterpret_cast<const bf16x8*>(abase + 96);
  float rs[4] = {0.f, 0.f, 0.f, 0.f};
  for (int jt = wv; jt < 63; jt += 4) {
    const ushort_t* bbase = gn_bf + (size_t)(jt * 16 + l15) * 128 + quad * 8;
    f32x4 d = {0.f, 0.f, 0.f, 0.f};
    d = __builtin_amdgcn_mfma_f32_16x16x32_bf16(af0, *reinterpret_cast<const bf16x8*>(bbase),      d, 0, 0, 0);
    d = __builtin_amdgcn_mfma_f32_16x16x32_bf16(af1, *reinterpret_cast<const bf16x8*>(bbase + 32), d, 0, 0, 0);
    d = __builtin_amdgcn_mfma_f32_16x16x32_bf16(af2, *reinterpret_cast<const bf16x8*>(bbase + 64), d, 0, 0, 0);
    d = __builtin_amdgcn_mfma_f32_16x16x32_bf16(af3, *reinterpret_cast<const bf16x8*>(bbase + 96), d, 0, 0, 0);
    int hot = 0;
    #pragma unroll
    for (int r = 0; r < 4; ++r) {
      float w = 0.f;
      if (d[r] > THRESH) { w = __expf(T_SOFT * (d[r] - 1.0f)); hot = 1; }  // shift cancels in normalize
      ushort_t wb = f2bf(w);
      W[(quad * 4 + r) * SW + jt * 16 + l15] = wb;
      rs[r] += bf2f(wb);    // rowsum of ROUNDED weights
    }
    if (hot) flags[jt] = 1;
  }
  #pragma unroll
  for (int r = 0; r < 4; ++r) {
    float v = rs[r];
    v += __shfl_xor(v, 1, 64); v += __shfl_xor(v, 2, 64);
    v += __shfl_xor(v, 4, 64); v += __shfl_xor(v, 8, 64);
    if (l15 == 0) atomicAdd(&rsum[quad * 4 + r], v);
  }
  __syncthreads();

  // phase 2: outs_strip = W @ [attrT; sum4(proto_redP); 0]^T (skip cold k-tiles)
  f32x4 acc[10];
  #pragma unroll
  for (int t = 0; t < 10; ++t) acc[t] = f32x4{0.f, 0.f, 0.f, 0.f};
  for (int s = 0; s < 32; ++s) {
    int f = flags[2 * s] | ((2 * s + 1 < 63) ? flags[2 * s + 1] : 0);
    if (!f) continue;
    bf16x8 a = *reinterpret_cast<bf16x8*>(W + l15 * SW + s * 32 + quad * 8);
    #pragma unroll
    for (int t = 0; t < 10; ++t) {
      int nrow = (wv * 10 + t) * 16 + l15;
      bf16x8 bfr;
      if (nrow < 312) {
        bfr = *reinterpret_cast<const bf16x8*>(attrT + (size_t)nrow * 1024 + s * 32 + quad * 8);
      } else if (nrow < 632) {
        const float* pp = proto_redP + (size_t)(nrow - 312) * 1024 + s * 32 + quad * 8;
        f32x4 x = *reinterpret_cast<const f32x4*>(pp)       + *reinterpret_cast<const f32x4*>(pp + PPR)
                + *reinterpret_cast<const f32x4*>(pp + 2 * PPR) + *reinterpret_cast<const f32x4*>(pp + 3 * PPR);
        f32x4 y = *reinterpret_cast<const f32x4*>(pp + 4)   + *reinterpret_cast<const f32x4*>(pp + PPR + 4)
                + *reinterpret_cast<const f32x4*>(pp + 2 * PPR + 4) + *reinterpret_cast<const f32x4*>(pp + 3 * PPR + 4);
        bfr = pack8(x, y);
      } else {
        union { unsigned u[4]; bf16x8 h; } z = {{0u, 0u, 0u, 0u}};
        bfr = z.h;
      }
      acc[t] = __builtin_amdgcn_mfma_f32_16x16x32_bf16(a, bfr, acc[t], 0, 0, 0);
    }
  }
  // normalize + bias -> OS (A-layout for phase 3)
  #pragma unroll
  for (int t = 0; t < 10; ++t) {
    int col = (wv * 10 + t) * 16 + l15;   // 0..639
    float bias = (col >= 312 && col < 624) ? slim_b[col - 312] : 0.f;
    #pragma unroll
    for (int r = 0; r < 4; ++r) {
      int row = quad * 4 + r;
      float inv = 1.f / fmaxf(rsum[row], 1e-30f);
      OS[row * SO + col] = f2bf(acc[t][r] * inv + bias);
    }
  }
  __syncthreads();

  // phase 3: ph_strip = OS(16x640) @ protowT(128x640)^T + proto_b
  f32x4 acc2[2];
  acc2[0] = f32x4{0.f, 0.f, 0.f, 0.f};
  acc2[1] = f32x4{0.f, 0.f, 0.f, 0.f};
  for (int s = 0; s < 20; ++s) {
    bf16x8 a = *reinterpret_cast<bf16x8*>(OS + l15 * SO + s * 32 + quad * 8);
    #pragma unroll
    for (int t = 0; t < 2; ++t) {
      int n = (wv * 2 + t) * 16 + l15;
      bf16x8 bfr = *reinterpret_cast<const bf16x8*>(protowT + (size_t)n * 640 + s * 32 + quad * 8);
      acc2[t] = __builtin_amdgcn_mfma_f32_16x16x32_bf16(a, bfr, acc2[t], 0, 0, 0);
    }
  }
  #pragma unroll
  for (int t = 0; t < 2; ++t) {
    int h = (wv * 2 + t) * 16 + l15;
    float pb = proto_b[h];
    #pragma unroll
    for (int r = 0; r < 4; ++r) {
      int gi = i0 + quad * 4 + r;
      if (gi < 1000) ph[(size_t)gi * 128 + h] = acc2[t][r] + pb;
    }
  }
}

// ---------------- final: out[b,c] = fc_b + sum_h relu(img_h[b,h]+ph[c,h]) * fc_w[h] ----------------
__global__ __launch_bounds__(256) void final_k(
    const float* __restrict__ img_hP, const float* __restrict__ ph,
    const float* __restrict__ fc_w, const float* __restrict__ fc_b,
    float* __restrict__ out) {
  __shared__ float ih[128][132];
  __shared__ float ps[64][132];
  __shared__ float ws_[128];
  int tid = threadIdx.x;
  int b0 = blockIdx.x * 128;
  int c0 = blockIdx.y * 64;
  for (int idx = tid; idx < 4096; idx += 256) {
    int row = idx >> 5, c4 = (idx & 31) * 4;
    const float* p = img_hP + (size_t)(b0 + row) * 128 + c4;
    f32x4 v = *reinterpret_cast<const f32x4*>(p)           + *reinterpret_cast<const f32x4*>(p + PIH)
            + *reinterpret_cast<const f32x4*>(p + 2 * PIH) + *reinterpret_cast<const f32x4*>(p + 3 * PIH);
    *reinterpret_cast<f32x4*>(&ih[row][c4]) = v;
  }
  for (int idx = tid; idx < 2048; idx += 256) {
    int row = idx >> 5, c4 = (idx & 31) * 4;
    int c = c0 + row;
    float4 v = make_float4(0.f, 0.f, 0.f, 0.f);
    if (c < 1000) v = *reinterpret_cast<const float4*>(ph + (size_t)c * 128 + c4);
    *reinterpret_cast<float4*>(&ps[row][c4]) = v;
  }
  if (tid < 128) ws_[tid] = fc_w[tid];
  __syncthreads();
  int tx = tid & 15, ty = tid >> 4;
  f32x2 acc[8][4] = {};
  const f32x2 zero2 = {0.f, 0.f};
  for (int h = 0; h < 128; h += 4) {
    float4 w4 = *reinterpret_cast<float4*>(&ws_[h]);
    f32x2 wlo = {w4.x, w4.y}, whi = {w4.z, w4.w};
    float4 a4[8], p4[4];
    #pragma unroll
    for (int i = 0; i < 8; ++i) a4[i] = *reinterpret_cast<float4*>(&ih[ty * 8 + i][h]);
    #pragma unroll
    for (int j = 0; j < 4; ++j) p4[j] = *reinterpret_cast<float4*>(&ps[tx * 4 + j][h]);
    #pragma unroll
    for (int i = 0; i < 8; ++i) {
      f32x2 alo = {a4[i].x, a4[i].y}, ahi = {a4[i].z, a4[i].w};
      #pragma unroll
      for (int j = 0; j < 4; ++j) {
        f32x2 plo = {p4[j].x, p4[j].y}, phi = {p4[j].z, p4[j].w};
        f32x2 t0 = __builtin_elementwise_max(alo + plo, zero2);
        f32x2 t1 = __builtin_elementwise_max(ahi + phi, zero2);
        acc[i][j] = acc[i][j] + t0 * wlo;
        acc[i][j] = acc[i][j] + t1 * whi;
      }
    }
  }
  float fb = fc_b[0];
  #pragma unroll
  for (int i = 0; i < 8; ++i) {
    int b = b0 + ty * 8 + i;
    int c = c0 + tx * 4;
    if (c < 1000) {
      float4 v = make_float4(acc[i][0].x + acc[i][0].y + fb, acc[i][1].x + acc[i][1].y + fb,
                             acc[i][2].x + acc[i][2].y + fb, acc[i][3].x + acc[i][3].y + fb);
      *reinterpret_cast<float4*>(out + (size_t)b * 1000 + c) = v;
    }
  }
}

extern "C" void kernel_launch(void* const* d_in, const int* in_sizes, int n_in,
                              void* d_out, int out_size, void* d_ws, size_t ws_size,
                              hipStream_t stream) {
  const float* image_feats = (const float*)d_in[0];   // [2048,2048]
  const float* img_proto   = (const float*)d_in[1];   // [1000,2048]
  const float* attributes  = (const float*)d_in[2];   // [1000,312]
  const float* att_g   = (const float*)d_in[4];       // [312,128]
  const float* slim_w  = (const float*)d_in[5];       // [2048,312]
  const float* slim_b  = (const float*)d_in[6];       // [312]
  const float* img_w   = (const float*)d_in[7];       // [2048,128]
  const float* proto_w = (const float*)d_in[8];       // [624,128]
  const float* proto_b = (const float*)d_in[9];       // [1,128]
  const float* fc_w    = (const float*)d_in[10];      // [128,1]
  const float* fc_b    = (const float*)d_in[11];      // [1]
  float* out = (float*)d_out;                         // [2048,1000]

  char* ws = (char*)d_ws;
  size_t o = 0;
  auto alloc = [&](size_t bytes) { size_t r = o; o += (bytes + 255) & ~(size_t)255; return r; };
  ushort_t* imgwT   = (ushort_t*)(ws + alloc(128ull * 2048 * 2));   // img_w^T bf16
  ushort_t* slimT   = (ushort_t*)(ws + alloc(320ull * 2048 * 2));   // slim_w^T bf16, rows 312..319 ZERO
  ushort_t* protowT = (ushort_t*)(ws + alloc(128ull * 640 * 2));    // proto_w^T bf16, K-pad zeros
  ushort_t* gn_bf   = (ushort_t*)(ws + alloc(1008ull * 128 * 2));   // normalized g bf16, tail zero
  ushort_t* attrT   = (ushort_t*)(ws + alloc(312ull * 1024 * 2));   // attributes^T bf16, cols 1000+ zero
  float* proto_redP = (float*)(ws + alloc(4ull * PPR * 4));         // proto_red^T fp32 partials x4
  float* img_hP    = (float*)(ws + alloc(4ull * PIH * 4));          // img_h fp32 partials x4
  float* ph        = (float*)(ws + alloc(1000ull * 128 * 4));

  // transposes (976) + attrT (320) + gn tail (1)
  tr3_k<<<1297, 256, 0, stream>>>(slim_w, slimT, img_w, imgwT, proto_w, protowT,
                                  attributes, attrT, gn_bf);

  // img_h splitK x4 direct-store (64) + proto_redT splitK x4 direct-store (96) + gn (125)
  mega_k<<<285, 256, 0, stream>>>(attributes, att_g, gn_bf,
                                  img_proto, slimT,
                                  image_feats, imgwT, img_hP, proto_redP);

  // sim -> softmax -> propagate -> ph (fused; sums proto partials on the fly)
  attn4_k<<<63, 256, 0, stream>>>(gn_bf, attrT, proto_redP, slim_b, protowT, proto_b, ph);

  // final (sums img_h partials on the fly)
  final_k<<<dim3(16, 16), 256, 0, stream>>>(img_hP, ph, fc_w, fc_b, out);
}